// Round 2
// baseline (334.451 us; speedup 1.0000x reference)
//
#include <hip/hip_runtime.h>
#include <math.h>

#define PI2f 6.28318530717958647692f

// B=16, Ci=Co=64, H=W=256, M1=M2=16. Modes j=0..31, freq f = (j<16) ? j : j-32.
//
// ALL scratch lives inside d_out (67,108,864 floats = 1024 regions x 65536):
//   Ft slice for bo : R(bo)  + [0, 2048)    (mix_k writes, inv_fused block bo reads)
//   X  slice for bi : R(bi)  + [2048, 3072) (fwd_fused writes, mix_k reads)
//   Wt[m], m<512    : R(m)   + [4096,12288) (wtrans writes, mix_k reads)
//   tw[w][k] table  : R(513) + [4096,12288) (twinit writes, fwd_fused reads)
// inv_fused block bo reads ONLY its own region's Ft slice (staged to LDS first),
// then overwrites its own region with the true output -> no cross-block hazard.

static constexpr size_t REG = 65536;
static constexpr size_t TW_OFF = (size_t)513 * REG + 4096;

// ---------------- twiddle table: tw[w][k] = e^{-2pi i w k / 256} ----------------
__global__ __launch_bounds__(256) void twinit(float* __restrict__ g) {
    int idx = blockIdx.x * 256 + threadIdx.x;       // 0..4095
    if (idx >= 256 * 16) return;
    int w = idx >> 4, k = idx & 15;
    int m = (k * w) & 255;                          // exact integer arg reduction
    float th = PI2f * (float)m / 256.0f;
    float s, c;
    sincosf(th, &s, &c);
    g[TW_OFF + (size_t)idx * 2]     = c;
    g[TW_OFF + (size_t)idx * 2 + 1] = -s;
}

// ---------------- weights -> mode-major, src-coalesced ----------------
// src layout (both w1,w2): complex idx s = ((i*64+o)*16 + xm)*16 + k
// dst: Wt[m][io] at R(m)+4096+io*2, m = j*16+k with j=xm (w1) / xm+16 (w2)
__global__ __launch_bounds__(256) void wtrans(const float* __restrict__ w1,
                                              const float* __restrict__ w2,
                                              float* g) {
    int s = blockIdx.x * 256 + threadIdx.x;         // 0..1048575
    int k = s & 15, xm = (s >> 4) & 15, io = s >> 8;
    float2 a = ((const float2*)w1)[s];
    float2 b = ((const float2*)w2)[s];
    size_t d1 = (size_t)(xm * 16 + k) * REG + 4096 + (size_t)io * 2;
    size_t d2 = (size_t)((xm + 16) * 16 + k) * REG + 4096 + (size_t)io * 2;
    *(float2*)(g + d1) = a;
    *(float2*)(g + d2) = b;
}

// ---------------- forward: W-DFT (16 modes) then H-DFT (32 modes), fused ----------------
// block = one (b,i) image. Output: X[m] complex at R(bi)+2048+m*2, m=j*16+k.
__global__ __launch_bounds__(256) void fwd_fused(const float* __restrict__ x,
                                                 float* g) {
    __shared__ float xs[256 * 33];                  // 256 rows x 32 w tile, pad->2-way
    __shared__ float As[256 * 16 * 2];              // A[h][k] complex, 32 KB
    const int t = threadIdx.x;
    const int bi = blockIdx.x;
    const float* xim = x + (size_t)bi * 65536;
    const float* tw = g + TW_OFF;

    float ar[16], ai[16];
#pragma unroll
    for (int k = 0; k < 16; k++) { ar[k] = 0.f; ai[k] = 0.f; }

    for (int w0 = 0; w0 < 256; w0 += 32) {
        __syncthreads();
#pragma unroll
        for (int q = 0; q < 8; q++) {
            int f = q * 256 + t;                    // float4 id 0..2047
            int r = f >> 3, c4 = (f & 7) * 4;
            float4 v = *(const float4*)(xim + (size_t)r * 256 + w0 + c4);
            xs[r * 33 + c4 + 0] = v.x;
            xs[r * 33 + c4 + 1] = v.y;
            xs[r * 33 + c4 + 2] = v.z;
            xs[r * 33 + c4 + 3] = v.w;
        }
        __syncthreads();
        const float* xr = xs + t * 33;              // thread t owns row h=t
#pragma unroll 4
        for (int w = 0; w < 32; w++) {
            float xv = xr[w];
            const float* tp = tw + (size_t)(w0 + w) * 32;   // wave-uniform
#pragma unroll
            for (int k = 0; k < 16; k++) {
                ar[k] = fmaf(xv, tp[2 * k],     ar[k]);
                ai[k] = fmaf(xv, tp[2 * k + 1], ai[k]);
            }
        }
    }
    // registers -> As[h=t][k]
    float* Ap = As + t * 32;
#pragma unroll
    for (int k = 0; k < 16; k++) { Ap[2 * k] = ar[k]; Ap[2 * k + 1] = ai[k]; }
    __syncthreads();

    // H-DFT: thread (jb = t>>4, k = t&15) computes modes j = jb, jb+16
    const int k = t & 15, jb = t >> 4;
    float* Xp = g + (size_t)bi * REG + 2048;
    for (int half = 0; half < 2; half++) {
        int j = jb + half * 16;
        int f = (j < 16) ? j : j - 32;
        float s, c;
        sincosf(-PI2f * (float)f / 256.0f, &s, &c); // ratio e^{-2pi i f/256}
        float er = 1.f, ei = 0.f, accr = 0.f, acci = 0.f;
        for (int h = 0; h < 256; h++) {
            float a_re = As[(h * 16 + k) * 2];
            float a_im = As[(h * 16 + k) * 2 + 1];
            accr = fmaf(a_re, er, fmaf(-a_im, ei, accr));
            acci = fmaf(a_re, ei, fmaf( a_im, er, acci));
            float nr = er * c - ei * s;
            ei = fmaf(er, s, ei * c);
            er = nr;
        }
        *(float2*)(Xp + (j * 16 + k) * 2) = make_float2(accr, acci);
    }
}

// ---------------- channel mixing: Ft[b][m][o] = sum_i X[b][i][m] * Wt[m][i][o] ----------------
__global__ __launch_bounds__(256) void mix_k(float* g) {
    const int wave = threadIdx.x >> 6, lane = threadIdx.x & 63;
    const int task = blockIdx.x * 4 + wave;         // 0..8191
    const int b = task >> 9, m = task & 511;
    const float* Xb = g + 2048 + (size_t)(b * 64) * REG + (size_t)m * 2;  // +i*REG, lane-uniform
    const float* Wp = g + (size_t)m * REG + 4096 + (size_t)lane * 2;      // +i*128
    float accr = 0.f, acci = 0.f;
    for (int i = 0; i < 64; i++) {
        float xr = Xb[(size_t)i * REG], xi = Xb[(size_t)i * REG + 1];
        float wr = Wp[i * 128],          wi = Wp[i * 128 + 1];
        accr = fmaf(xr, wr, fmaf(-xi, wi, accr));
        acci = fmaf(xr, wi, fmaf( xi, wr, acci));
    }
    float* Fp = g + (size_t)(b * 64 + lane) * REG + (size_t)m * 2;        // Ft slice of bo
    Fp[0] = accr;
    Fp[1] = acci;
}

// ---------------- inverse: H-iDFT (32->256) + irfft-W (16->256), fused ----------------
// block = one bo region. Thread t owns output row h=t.
__global__ __launch_bounds__(256) void inv_fused(float* g) {
    __shared__ float Fs[2048];                      // Ft slice, 8 KB
    __shared__ float phS[512];                      // e^{+2pi i t/256}, 2 KB
    __shared__ float T[256 * 17];                   // transpose tile, 17 KB
    const int t = threadIdx.x;
    const int bo = blockIdx.x;
    float* regn = g + (size_t)bo * REG;

    // stage own Ft slice to LDS BEFORE any output write
#pragma unroll
    for (int q = 0; q < 4; q++) {
        int idx = q * 256 + t;                      // 0..1023 complex
        float2 v = *(const float2*)(regn + (size_t)idx * 2);
        *(float2*)(Fs + idx * 2) = v;
    }
    {
        float s, c;
        sincosf(PI2f * (float)t / 256.0f, &s, &c);
        phS[t * 2] = c; phS[t * 2 + 1] = s;
    }
    __syncthreads();

    // phase 1: Y[h=t][k] = sum_f Ft[j(f)][k] e^{+2pi i f t/256}, f=-16..15
    float Yr[16], Yi[16];
#pragma unroll
    for (int k = 0; k < 16; k++) { Yr[k] = 0.f; Yi[k] = 0.f; }
    float es, ec;
    sincosf(-PI2f * (float)(t & 15) / 16.0f, &es, &ec); // e^{-2pi i 16 t/256}
    const float rc = phS[t * 2], rs = phS[t * 2 + 1];   // ratio e^{+2pi i t/256}
    float er = ec, ei = es;
    for (int sdx = 0; sdx < 32; sdx++) {                // f = sdx-16
        int j = (sdx < 16) ? sdx + 16 : sdx - 16;
        const float* fj = Fs + j * 32;
#pragma unroll
        for (int k = 0; k < 16; k++) {
            float fr = fj[2 * k], fi = fj[2 * k + 1];
            Yr[k] = fmaf(fr, er, fmaf(-fi, ei, Yr[k]));
            Yi[k] = fmaf(fr, ei, fmaf( fi, er, Yi[k]));
        }
        float nr = er * rc - ei * rs;
        ei = fmaf(er, rs, ei * rc);
        er = nr;
    }

    // phase 2: out[t][w] = (1/65536)*(Yr0 + 2*sum_{k>=1}(Yrk cos - Yik sin)(2pi k w/256))
    const float SCL = 2.0f / 65536.0f;
    for (int cc = 0; cc < 16; cc++) {
        int w0 = cc * 16;
        float vals[16];
#pragma unroll
        for (int ww = 0; ww < 16; ww++) {
            int w = w0 + ww;
            float c1 = phS[w * 2], s1 = phS[w * 2 + 1]; // cos/sin(2pi w/256)
            float c2 = 2.0f * c1;
            float acc = fmaf(0.5f, Yr[0], fmaf(Yr[1], c1, -Yi[1] * s1));
            float Cpp = 1.f, Cp = c1, Spp = 0.f, Sp = s1;
#pragma unroll
            for (int k = 2; k < 16; k++) {              // Chebyshev: T_k = 2c T_{k-1} - T_{k-2}
                float Cn = fmaf(c2, Cp, -Cpp);
                float Sn = fmaf(c2, Sp, -Spp);
                acc = fmaf(Yr[k], Cn, fmaf(-Yi[k], Sn, acc));
                Cpp = Cp; Cp = Cn; Spp = Sp; Sp = Sn;
            }
            vals[ww] = acc * SCL;
        }
        __syncthreads();                                // T reuse guard
#pragma unroll
        for (int ww = 0; ww < 16; ww++) T[t * 17 + ww] = vals[ww];
        __syncthreads();
        // coalesced store: lane covers (row = it*16 + t>>4, col = t&15)
        const int col = t & 15, rb = t >> 4;
#pragma unroll
        for (int it = 0; it < 16; it++) {
            int row = it * 16 + rb;
            regn[(size_t)row * 256 + w0 + col] = T[row * 17 + col];
        }
    }
}

extern "C" void kernel_launch(void* const* d_in, const int* in_sizes, int n_in,
                              void* d_out, int out_size, void* d_ws, size_t ws_size,
                              hipStream_t stream) {
    const float* x  = (const float*)d_in[0];
    const float* w1 = (const float*)d_in[1];
    const float* w2 = (const float*)d_in[2];
    float* g = (float*)d_out;
    (void)d_ws; (void)ws_size;

    twinit   <<<16,   256, 0, stream>>>(g);
    wtrans   <<<4096, 256, 0, stream>>>(w1, w2, g);
    fwd_fused<<<1024, 256, 0, stream>>>(x, g);
    mix_k    <<<2048, 256, 0, stream>>>(g);
    inv_fused<<<1024, 256, 0, stream>>>(g);
}